// Round 11
// baseline (311.927 us; speedup 1.0000x reference)
//
#include <hip/hip_runtime.h>

#define GN_EPS 1e-5f

constexpr int NB   = 64;             // graphs
constexpr int EPG  = 16384;          // edges per graph (static)
constexpr int ETOT = NB * EPG;       // 1048576 edges
constexpr int NTOT = 64 * 1024;      // original nodes

// ---------------------------------------------------------------- cmap init (identity)
__global__ void cmap_init_kernel(int* __restrict__ cmap) {
    int i = blockIdx.x * blockDim.x + threadIdx.x;
    if (i < NTOT) cmap[i] = i;
}

// ---------------------------------------------------------------- fused per-graph CSR build
// One 1024-thread block per graph; reads ORIGINAL edges + composed cmap.
// LDS count -> wave-shfl scan -> fill (endpoints cached in registers).
template <int NPG>   // nodes per graph this layer: 1024 / 512 / 256
__global__ __launch_bounds__(1024) void csr_build_kernel(
        const int* __restrict__ ei, const int* __restrict__ cmap,
        int* __restrict__ cnt, int* __restrict__ offs, float* __restrict__ dinv,
        int* __restrict__ csr_src) {
    __shared__ int lcnt[NPG];
    __shared__ int wsum[16];
    constexpr int NW = NPG / 64;
    const int g = blockIdx.x;
    const int t = threadIdx.x;           // 1024 threads
    const int ebase = g * EPG;
    constexpr int EPT = EPG / 1024;      // 16

    for (int i = t; i < NPG; i += 1024) lcnt[i] = 0;
    __syncthreads();

    int ms_[EPT], md_[EPT];
#pragma unroll
    for (int i = 0; i < EPT; i++) {
        int e = ebase + t + i * 1024;                // coalesced
        int s = cmap[ei[e]];
        int d = cmap[ei[ETOT + e]];
        bool ok = (s >= 0) && (d >= 0);
        ms_[i] = ok ? s : -1;
        md_[i] = ok ? (d - g * NPG) : 0;
        if (ok) atomicAdd(&lcnt[d - g * NPG], 1);
    }
    __syncthreads();

    // ---- exclusive scan via wave shfl
    const int lane = t & 63;
    const int wid  = t >> 6;
    int orig = (t < NPG) ? lcnt[t] : 0;
    int v = orig;
#pragma unroll
    for (int d = 1; d < 64; d <<= 1) {
        int u = __shfl_up(v, d);
        if (lane >= d) v += u;
    }
    if (lane == 63) wsum[wid] = v;
    __syncthreads();
    if (wid == 0) {
        int wv = (lane < NW) ? wsum[lane] : 0;
#pragma unroll
        for (int d = 1; d < 16; d <<= 1) {
            int u = __shfl_up(wv, d);
            if (lane >= d) wv += u;
        }
        if (lane < NW) wsum[lane] = wv;
    }
    __syncthreads();
    if (t < NPG) {
        int incl = v + ((wid > 0) ? wsum[wid - 1] : 0);
        int excl = incl - orig;
        cnt[g * NPG + t]  = orig;
        offs[g * NPG + t] = ebase + excl;
        dinv[g * NPG + t] = rsqrtf(1.0f + (float)orig);
        lcnt[t] = excl;                              // fill cursor
    }
    __syncthreads();

#pragma unroll
    for (int i = 0; i < EPT; i++) {
        if (ms_[i] >= 0) {
            int pos = atomicAdd(&lcnt[md_[i]], 1);
            csr_src[ebase + pos] = ms_[i];
        }
    }
}

// ---------------------------------------------------------------- weighted CSR gather (PRE-GEMM)
// z[v] = dinv[v] * ( dinv[v]*x[v] + sum_src dinv[src]*x[src] )   (width = din)
template <int D4, int NPB>   // D4: float4s per row (25 or 32); NPB nodes/block
__global__ __launch_bounds__(256) void gather_kernel(
        const float* __restrict__ x, const int* __restrict__ cnt,
        const int* __restrict__ offs, const float* __restrict__ dinv,
        const int* __restrict__ csr_src, float* __restrict__ z, int n, int bpg) {
    int bid   = blockIdx.x;
    int xcd   = bid & 7;
    int slot  = bid >> 3;
    int graph = xcd + 8 * (slot / bpg);
    int local = slot % bpg;
    int vb    = graph * bpg + local;

    int grp = threadIdx.x / D4;
    int f4  = threadIdx.x % D4;
    if (grp >= NPB) return;
    int v = vb * NPB + grp;
    if (v >= n) return;

    const float4* x4 = reinterpret_cast<const float4*>(x);
    int st = offs[v];
    int c  = cnt[v];
    float dv = dinv[v];
    float4 xv = x4[(size_t)v * D4 + f4];
    float4 acc = {xv.x * dv, xv.y * dv, xv.z * dv, xv.w * dv};   // self: dinv[v]*x[v]
    int j = 0;
    for (; j + 4 <= c; j += 4) {
        int s0 = csr_src[st + j],     s1 = csr_src[st + j + 1];
        int s2 = csr_src[st + j + 2], s3 = csr_src[st + j + 3];
        float d0 = dinv[s0], d1 = dinv[s1], d2 = dinv[s2], d3 = dinv[s3];
        float4 h0 = x4[(size_t)s0 * D4 + f4];
        float4 h1 = x4[(size_t)s1 * D4 + f4];
        float4 h2 = x4[(size_t)s2 * D4 + f4];
        float4 h3 = x4[(size_t)s3 * D4 + f4];
        acc.x += h0.x * d0 + h1.x * d1 + h2.x * d2 + h3.x * d3;
        acc.y += h0.y * d0 + h1.y * d1 + h2.y * d2 + h3.y * d3;
        acc.z += h0.z * d0 + h1.z * d1 + h2.z * d2 + h3.z * d3;
        acc.w += h0.w * d0 + h1.w * d1 + h2.w * d2 + h3.w * d3;
    }
    for (; j < c; j++) {
        int s0 = csr_src[st + j];
        float d0 = dinv[s0];
        float4 h0 = x4[(size_t)s0 * D4 + f4];
        acc.x += h0.x * d0; acc.y += h0.y * d0; acc.z += h0.z * d0; acc.w += h0.w * d0;
    }
    float4 o = {acc.x * dv, acc.y * dv, acc.z * dv, acc.w * dv};
    reinterpret_cast<float4*>(z)[(size_t)v * D4 + f4] = o;
}

// ---------------------------------------------------------------- GEMM  C[M,N] = A[M,K] @ W[K,N] + b[col]
__global__ __launch_bounds__(256) void gemm128_kernel(const float* __restrict__ A,
                                                      const float* __restrict__ W,
                                                      const float* __restrict__ Bias,
                                                      float* __restrict__ C,
                                                      int M, int N, int K) {
    __shared__ float As[16][132];
    __shared__ float Bs[16][132];
    const int bm = blockIdx.x * 128;
    const int bn = blockIdx.y * 128;
    const int tid = threadIdx.x;
    const int tx = tid & 15, ty = tid >> 4;

    const int arow = tid >> 1;          // 0..127
    const int ak   = (tid & 1) * 8;     // 0 or 8
    const int brow = tid >> 5;          // 0..7
    const int bc4  = (tid & 31) * 4;    // 0..124

    float acc[2][2][4][4] = {};

    for (int k0 = 0; k0 < K; k0 += 16) {
        {   // stage A (transpose to [k][m])
            const float* ap = A + (size_t)(bm + arow) * K + k0 + ak;
            float4 a0 = {0,0,0,0}, a1 = {0,0,0,0};
            if (k0 + ak < K)     a0 = *reinterpret_cast<const float4*>(ap);
            if (k0 + ak + 4 < K) a1 = *reinterpret_cast<const float4*>(ap + 4);
            As[ak + 0][arow] = a0.x; As[ak + 1][arow] = a0.y;
            As[ak + 2][arow] = a0.z; As[ak + 3][arow] = a0.w;
            As[ak + 4][arow] = a1.x; As[ak + 5][arow] = a1.y;
            As[ak + 6][arow] = a1.z; As[ak + 7][arow] = a1.w;
        }
        {   // stage B
            float4 b0 = {0,0,0,0}, b1 = {0,0,0,0};
            if (k0 + brow < K)
                b0 = *reinterpret_cast<const float4*>(W + (size_t)(k0 + brow) * N + bn + bc4);
            if (k0 + brow + 8 < K)
                b1 = *reinterpret_cast<const float4*>(W + (size_t)(k0 + brow + 8) * N + bn + bc4);
            *reinterpret_cast<float4*>(&Bs[brow][bc4])     = b0;
            *reinterpret_cast<float4*>(&Bs[brow + 8][bc4]) = b1;
        }
        __syncthreads();
#pragma unroll
        for (int k = 0; k < 16; k++) {
            float4 a0 = *reinterpret_cast<const float4*>(&As[k][ty * 4]);
            float4 a1 = *reinterpret_cast<const float4*>(&As[k][64 + ty * 4]);
            float4 b0 = *reinterpret_cast<const float4*>(&Bs[k][tx * 4]);
            float4 b1 = *reinterpret_cast<const float4*>(&Bs[k][64 + tx * 4]);
            const float av[2][4] = {{a0.x, a0.y, a0.z, a0.w}, {a1.x, a1.y, a1.z, a1.w}};
            const float bv[2][4] = {{b0.x, b0.y, b0.z, b0.w}, {b1.x, b1.y, b1.z, b1.w}};
#pragma unroll
            for (int qi = 0; qi < 2; qi++)
#pragma unroll
                for (int qj = 0; qj < 2; qj++)
#pragma unroll
                    for (int i = 0; i < 4; i++)
#pragma unroll
                        for (int j = 0; j < 4; j++)
                            acc[qi][qj][i][j] += av[qi][i] * bv[qj][j];
        }
        __syncthreads();
    }
    float4 bb[2];
    bb[0] = *reinterpret_cast<const float4*>(&Bias[bn + tx * 4]);
    bb[1] = *reinterpret_cast<const float4*>(&Bias[bn + 64 + tx * 4]);
#pragma unroll
    for (int qi = 0; qi < 2; qi++)
#pragma unroll
        for (int i = 0; i < 4; i++) {
            int row = bm + qi * 64 + ty * 4 + i;
#pragma unroll
            for (int qj = 0; qj < 2; qj++) {
                float4 o = {acc[qi][qj][i][0] + bb[qj].x, acc[qi][qj][i][1] + bb[qj].y,
                            acc[qi][qj][i][2] + bb[qj].z, acc[qi][qj][i][3] + bb[qj].w};
                *reinterpret_cast<float4*>(&C[(size_t)row * N + bn + qj * 64 + tx * 4]) = o;
            }
        }
}

// ---------------------------------------------------------------- graphnorm partial sums (slot writes)
template <int D4>   // 32 or 64
__global__ __launch_bounds__(256) void gn_partial_kernel(
        const float* __restrict__ x, float* __restrict__ sum1, float* __restrict__ sum2,
        int n_per) {
    constexpr int GROUPS = 256 / D4;
    __shared__ float4 l1[256];
    __shared__ float4 l2[256];
    int g = blockIdx.x >> 3;          // graph
    int ch = blockIdx.x & 7;          // node chunk (8 chunks)
    int f4 = threadIdx.x % D4;
    int grp = threadIdx.x / D4;
    int chunk = n_per / 8;
    int base = g * n_per + ch * chunk;
    const float4* x4 = reinterpret_cast<const float4*>(x);
    float4 s1 = {0.f, 0.f, 0.f, 0.f}, s2 = {0.f, 0.f, 0.f, 0.f};
    for (int i = grp; i < chunk; i += GROUPS) {
        float4 v = x4[(size_t)(base + i) * D4 + f4];
        s1.x += v.x; s1.y += v.y; s1.z += v.z; s1.w += v.w;
        s2.x += v.x * v.x; s2.y += v.y * v.y; s2.z += v.z * v.z; s2.w += v.w * v.w;
    }
    int t = threadIdx.x;
    l1[t] = s1; l2[t] = s2;
    __syncthreads();
    for (int str = 128; str >= D4; str >>= 1) {
        if (t < str) {
            float4 a = l1[t + str], b2 = l2[t + str];
            l1[t].x += a.x; l1[t].y += a.y; l1[t].z += a.z; l1[t].w += a.w;
            l2[t].x += b2.x; l2[t].y += b2.y; l2[t].z += b2.z; l2[t].w += b2.w;
        }
        __syncthreads();
    }
    if (t < D4) {
        size_t slot = (size_t)(g * 8 + ch) * (D4 * 4) + t * 4;
        *reinterpret_cast<float4*>(&sum1[slot]) = l1[t];
        *reinterpret_cast<float4*>(&sum2[slot]) = l2[t];
    }
}

// ---------------------------------------------------------------- 1/||p|| for all 3 layers in one launch
__global__ void pnorm3_kernel(const float* __restrict__ p0, const float* __restrict__ p1,
                              const float* __restrict__ p2, int d0, int d1, int d2,
                              float* __restrict__ out) {
    __shared__ float red[256];
    const float* p = (blockIdx.x == 0) ? p0 : (blockIdx.x == 1) ? p1 : p2;
    int d          = (blockIdx.x == 0) ? d0 : (blockIdx.x == 1) ? d1 : d2;
    int t = threadIdx.x;
    float v = (t < d) ? p[t] : 0.0f;
    red[t] = v * v;
    __syncthreads();
    for (int s = 128; s; s >>= 1) {
        if (t < s) red[t] += red[t + s];
        __syncthreads();
    }
    if (t == 0) out[blockIdx.x] = 1.0f / sqrtf(red[0]);
}

// ---------------------------------------------------------------- graphnorm finalize + apply + relu + score
// Stats reduced from 8 chunk-slots into LDS, then applied. Replaces gn_final.
template <int DO>
__global__ __launch_bounds__(256) void gn_apply_score_kernel(
        float* __restrict__ x, const float* __restrict__ sum1, const float* __restrict__ sum2,
        const float* __restrict__ ms, const float* __restrict__ w,
        const float* __restrict__ bias, const float* __restrict__ p,
        const float* __restrict__ pinv, float* __restrict__ score, int n_per) {
    constexpr int V = DO / 64;
    __shared__ float scm[DO];
    __shared__ float ssr[DO];
    int node = blockIdx.x * 4 + (threadIdx.x >> 6);
    int lane = threadIdx.x & 63;
    int g = node / n_per;
    float inv_n = 1.0f / (float)n_per;
    // cooperative per-graph stats into LDS
    for (int f = threadIdx.x; f < DO; f += 256) {
        float s1 = 0.f, s2 = 0.f;
#pragma unroll
        for (int ch = 0; ch < 8; ch++) {
            s1 += sum1[(size_t)(g * 8 + ch) * DO + f];
            s2 += sum2[(size_t)(g * 8 + ch) * DO + f];
        }
        float mean = s1 * inv_n;
        float ex2  = s2 * inv_n;
        float m = ms[f];
        float var = ex2 - 2.f * m * mean * mean + m * m * mean * mean;
        scm[f] = m * mean;
        ssr[f] = w[f] * rsqrtf(var + GN_EPS);
    }
    __syncthreads();

    float*       xr = x + (size_t)node * DO + lane * V;
    const float* bb = bias + lane * V;
    const float* pp = p + lane * V;
    float dot = 0.f;
#pragma unroll
    for (int i = 0; i < V; i++) {
        int f = lane * V + i;
        float y = (xr[i] - scm[f]) * ssr[f] + bb[i];
        y = fmaxf(y, 0.0f);
        xr[i] = y;
        dot += y * pp[i];
    }
#pragma unroll
    for (int off = 32; off; off >>= 1) dot += __shfl_xor(dot, off);
    if (lane == 0) score[node] = tanhf(dot * pinv[0]);
}

// ---------------------------------------------------------------- top-k via radix select
template <int N, int K>
__global__ __launch_bounds__(1024) void topk_radix_kernel(
        const float* __restrict__ score, int* __restrict__ mapping,
        int* __restrict__ inv) {
    __shared__ int hist[256];
    __shared__ int sscan[N];
    __shared__ int sbyte, sneed;
    const int g = blockIdx.x;
    const int t = threadIdx.x;       // blockDim == N
    float sc = score[g * N + t];
    unsigned u = __float_as_uint(sc);
    unsigned key = (u & 0x80000000u) ? ~u : (u | 0x80000000u);   // monotone

    unsigned prefix = 0;
    int need = K;
#pragma unroll
    for (int shift = 24; shift >= 0; shift -= 8) {
        if (t < 256) hist[t] = 0;
        __syncthreads();
        unsigned hm = (shift == 24) ? 0u : (0xFFFFFFFFu << (shift + 8));
        if ((key & hm) == (prefix & hm))
            atomicAdd(&hist[(key >> shift) & 255], 1);
        __syncthreads();
        if (t < 256) sscan[t] = hist[t];
        __syncthreads();
        for (int d = 1; d < 256; d <<= 1) {
            int x = (t < 256 && t + d < 256) ? sscan[t + d] : 0;
            __syncthreads();
            if (t < 256) sscan[t] += x;
            __syncthreads();
        }
        if (t < 256) {
            int ge  = sscan[t];
            int gt_ = (t + 1 < 256) ? sscan[t + 1] : 0;
            if (ge >= need && gt_ < need) { sbyte = t; sneed = need - gt_; }
        }
        __syncthreads();
        prefix |= ((unsigned)sbyte << shift);
        need = sneed;
        __syncthreads();
    }
    bool gt = key > prefix;
    bool eq = (key == prefix);
    sscan[t] = (gt ? (1 << 16) : 0) | (eq ? 1 : 0);
    __syncthreads();
    for (int d = 1; d < N; d <<= 1) {
        int x = (t >= d) ? sscan[t - d] : 0;
        __syncthreads();
        sscan[t] += x;
        __syncthreads();
    }
    int incl   = sscan[t];
    int gtrank = (incl >> 16) - (gt ? 1 : 0);
    int eqrank = (incl & 0xFFFF) - (eq ? 1 : 0);
    int cntGT  = K - need;
    bool sel = gt || (eq && (eqrank < need));
    int old_g = g * N + t;
    if (sel) {
        int slot = gt ? gtrank : (cntGT + eqrank);
        mapping[old_g] = g * K + slot;
        inv[g * K + slot] = old_g;
    } else {
        mapping[old_g] = -1;
    }
}

// ---------------------------------------------------------------- permute+scale, fused with cmap composition
__global__ void permute_compose_kernel(const float* __restrict__ x, const int* __restrict__ inv,
                                       const float* __restrict__ score, float* __restrict__ xn,
                                       int total, int ldof4,
                                       int* __restrict__ cmap, const int* __restrict__ mapping) {
    int t = blockIdx.x * blockDim.x + threadIdx.x;
    if (t < total) {
        int node = t >> ldof4;
        int f4   = t & ((1 << ldof4) - 1);
        int dof4 = 1 << ldof4;
        int old = inv[node];
        float sc = score[old];
        float4 v = reinterpret_cast<const float4*>(x)[(size_t)old * dof4 + f4];
        float4 o = {v.x * sc, v.y * sc, v.z * sc, v.w * sc};
        reinterpret_cast<float4*>(xn)[t] = o;
    }
    if (t < NTOT) {
        int c = cmap[t];
        cmap[t] = (c >= 0) ? mapping[c] : -1;
    }
}

// ---------------------------------------------------------------- final select + mean/max pool (fused)
// Reads layer-2 output X1 via inv (128 selected nodes/graph), scales by score.
__global__ __launch_bounds__(1024) void pool_sel_kernel(const float* __restrict__ x,
                                                        const int* __restrict__ inv,
                                                        const float* __restrict__ score,
                                                        float* __restrict__ out) {
    __shared__ float ssum[1024];
    __shared__ float smax[1024];
    int g = blockIdx.x;
    int f = threadIdx.x & 255;
    int ch = threadIdx.x >> 8;       // 0..3
    float s = 0.f, mx = -INFINITY;
    for (int i = ch; i < 128; i += 4) {
        int old = inv[g * 128 + i];
        float sc = score[old];
        float v = x[(size_t)old * 256 + f] * sc;
        s += v;
        mx = fmaxf(mx, v);
    }
    ssum[threadIdx.x] = s;
    smax[threadIdx.x] = mx;
    __syncthreads();
    if (ch == 0) {
#pragma unroll
        for (int c = 1; c < 4; c++) {
            s  += ssum[f + c * 256];
            mx  = fmaxf(mx, smax[f + c * 256]);
        }
        out[g * 512 + f]       = s / 128.0f;
        out[g * 512 + 256 + f] = mx;
    }
}

// ================================================================ host
static inline int cdiv_h(int a, int b) { return (a + b - 1) / b; }

extern "C" void kernel_launch(void* const* d_in, const int* in_sizes, int n_in,
                              void* d_out, int out_size, void* d_ws, size_t ws_size,
                              hipStream_t stream) {
    (void)in_sizes; (void)n_in; (void)out_size; (void)ws_size;

    const float* x_in = (const float*)d_in[0];
    const int*   ei   = (const int*)d_in[1];
    // d_in[2] = batch (unused, equal-sized graphs)
    const float* Wm[3]  = {(const float*)d_in[3],  (const float*)d_in[9],  (const float*)d_in[15]};
    const float* bv[3]  = {(const float*)d_in[4],  (const float*)d_in[10], (const float*)d_in[16]};
    const float* gnw[3] = {(const float*)d_in[5],  (const float*)d_in[11], (const float*)d_in[17]};
    const float* gnb[3] = {(const float*)d_in[6],  (const float*)d_in[12], (const float*)d_in[18]};
    const float* gnm[3] = {(const float*)d_in[7],  (const float*)d_in[13], (const float*)d_in[19]};
    const float* pv[3]  = {(const float*)d_in[8],  (const float*)d_in[14], (const float*)d_in[20]};

    // workspace carve
    size_t off = 0;
    auto alloc = [&](size_t bytes) {
        void* p = (char*)d_ws + off;
        off += (bytes + 255) & ~(size_t)255;
        return p;
    };
    float* X1      = (float*)alloc((size_t)65536 * 128 * 4);   // gemm out (L2: 16384x256)
    float* Z       = (float*)alloc((size_t)65536 * 128 * 4);   // gather out (pre-gemm)
    float* X2      = (float*)alloc((size_t)32768 * 128 * 4);   // permuted x for next layer
    int*   csr_src = (int*)alloc((size_t)ETOT * 4);
    int*   cmap    = (int*)alloc(NTOT * 4);
    int*   cnt     = (int*)alloc(65536 * 4);
    int*   offs    = (int*)alloc(65536 * 4);
    float* dinv    = (float*)alloc(65536 * 4);
    float* score   = (float*)alloc(65536 * 4);
    int*   mapping = (int*)alloc(65536 * 4);
    int*   inv     = (int*)alloc(32768 * 4);
    float* sum1    = (float*)alloc(64 * 8 * 256 * 4);   // per-chunk slots
    float* sum2    = (float*)alloc(64 * 8 * 256 * 4);
    float* pinv    = (float*)alloc(256);

    const int nper[4] = {1024, 512, 256, 128};
    const int din[3]  = {100, 128, 128};
    const int dof[3]  = {128, 128, 256};

    cmap_init_kernel<<<NTOT / 256, 256, 0, stream>>>(cmap);
    pnorm3_kernel<<<3, 256, 0, stream>>>(pv[0], pv[1], pv[2], dof[0], dof[1], dof[2], pinv);

    for (int L = 0; L < 3; L++) {
        const int n    = NB * nper[L];
        const int k    = nper[L + 1];
        const int nn   = NB * k;
        const int D    = dof[L];
        const int dof4 = D / 4;
        const int ldof4 = (dof4 == 32) ? 5 : 6;
        const float* xin = (L == 0) ? x_in : X2;

        // ---- fused CSR build from original edges + cmap
        if (nper[L] == 1024)
            csr_build_kernel<1024><<<NB, 1024, 0, stream>>>(ei, cmap, cnt, offs, dinv, csr_src);
        else if (nper[L] == 512)
            csr_build_kernel<512><<<NB, 1024, 0, stream>>>(ei, cmap, cnt, offs, dinv, csr_src);
        else
            csr_build_kernel<256><<<NB, 1024, 0, stream>>>(ei, cmap, cnt, offs, dinv, csr_src);

        // ---- weighted aggregate on raw x (din-wide):  Z = dinv*(dinv*x + sum dinv*x[src])
        {
            const int NPB = 8;
            const int bpg = nper[L] / NPB;
            if (L == 0)
                gather_kernel<25, 8><<<n / NPB, 256, 0, stream>>>(xin, cnt, offs, dinv,
                                                                  csr_src, Z, n, bpg);
            else
                gather_kernel<32, 8><<<n / NPB, 256, 0, stream>>>(xin, cnt, offs, dinv,
                                                                  csr_src, Z, n, bpg);
        }

        // ---- X1 = Z @ W + b
        gemm128_kernel<<<dim3(n / 128, D / 128), 256, 0, stream>>>(Z, Wm[L], bv[L], X1,
                                                                   n, D, din[L]);

        // ---- graphnorm stats
        if (dof4 == 32)
            gn_partial_kernel<32><<<NB * 8, 256, 0, stream>>>(X1, sum1, sum2, nper[L]);
        else
            gn_partial_kernel<64><<<NB * 8, 256, 0, stream>>>(X1, sum1, sum2, nper[L]);

        // ---- graphnorm finalize+apply+relu+score (fused)
        if (D == 128)
            gn_apply_score_kernel<128><<<n / 4, 256, 0, stream>>>(X1, sum1, sum2, gnm[L],
                                                                  gnw[L], gnb[L], pv[L],
                                                                  pinv + L, score, nper[L]);
        else
            gn_apply_score_kernel<256><<<n / 4, 256, 0, stream>>>(X1, sum1, sum2, gnm[L],
                                                                  gnw[L], gnb[L], pv[L],
                                                                  pinv + L, score, nper[L]);

        // ---- top-k pooling (radix select)
        if (nper[L] == 1024)
            topk_radix_kernel<1024, 512><<<NB, 1024, 0, stream>>>(score, mapping, inv);
        else if (nper[L] == 512)
            topk_radix_kernel<512, 256><<<NB, 512, 0, stream>>>(score, mapping, inv);
        else
            topk_radix_kernel<256, 128><<<NB, 256, 0, stream>>>(score, mapping, inv);

        if (L < 2) {
            // permute+scale into X2, and compose cmap, in one launch
            int total = nn * dof4;
            permute_compose_kernel<<<cdiv_h(total, 256), 256, 0, stream>>>(
                X1, inv, score, X2, total, ldof4, cmap, mapping);
        } else {
            // final select + mean/max pool -> [64, 512]
            pool_sel_kernel<<<NB, 1024, 0, stream>>>(X1, inv, score, (float*)d_out);
        }
    }
}